// Round 14
// baseline (185.403 us; speedup 1.0000x reference)
//
#include <hip/hip_runtime.h>

#define NB     8192
#define HDIM   64
#define SEQ    180
#define MT     16     // batch rows per block
#define SB     72     // bf16 LDS row stride: 144 B, 16B-aligned (SB=68 regressed: misaligned b128)
#define XSP    100    // xs prologue row stride (floats)

typedef __bf16 bf16x8 __attribute__((ext_vector_type(8)));
typedef __bf16 bf16x4 __attribute__((ext_vector_type(4)));
typedef float  f32x4  __attribute__((ext_vector_type(4)));

#define L2E 1.44269504088896340736f

__device__ __forceinline__ float tanh_f(float x) {
    float e = __builtin_amdgcn_exp2f((2.0f * L2E) * x);
    return 1.0f - 2.0f * __builtin_amdgcn_rcpf(1.0f + e);
}

#define MFMA __builtin_amdgcn_mfma_f32_16x16x32_bf16

// In-loop barrier: LDS-only drain (R17: neutral vs __syncthreads; kept so the
// deferred head's global store floats across barriers).
#define BAR_LDS() asm volatile("s_waitcnt lgkmcnt(0)\n\ts_barrier" ::: "memory")

// R27 = R24 (best, 101us) + MINIMAL N-gate fold, strictly register-neutral:
//  - whi[2] (w_hh_N) pre-scaled by 2*L2E at load (prologue, free);
//  - bn4 scaled by 2*L2E IN PLACE (same 4 regs, zero new constants --
//    R21 failed by keeping cNb AND cN4; R26 failed by f32x2 hand-threading
//    which RAISED pressure to 132 VGPR and crossed the 128 occupancy cliff);
//  - tN = fma(rg, aN, cN4): -4 v_mul per wave-step.
// This is the LAST register-neutral issue cut in the inventory. All other
// branches measured and closed: sync tools (R15 sleep / R20 toggled prio /
// R23 split barriers / R25 static prio: all ~neutral), dual-chain (R16/R22),
// tile shrink (R19), register-costly folds (R21/R26: VGPR cliff).
// Numerics: R26 passed with this exact N-scaling, absmax 0.00390625.
// Pre-commit: neutral here => ~101us is this decomposition's latency floor.
__global__ __launch_bounds__(256) void gru_all(
        const float* __restrict__ z, const int* __restrict__ labels,
        const float* __restrict__ embed_w, const float* __restrict__ fc_w,
        const float* __restrict__ fc_b, const float* __restrict__ w_hh,
        const float* __restrict__ b_ih, const float* __restrict__ b_hh,
        const float* __restrict__ out_w, const float* __restrict__ out_b,
        float* __restrict__ out) {
    __shared__ __align__(16) __bf16 hbuf[2][MT * SB];  // [buf] bf16(h)
    __shared__ __align__(16) float  xs[MT * XSP];      // h0 input [z|embed]

    const int t = threadIdx.x;
    const int w = t >> 6;          // wave 0..3
    const int l = t & 63;
    const int q = l >> 4;          // quad 0..3
    const int n16 = l & 15;
    const int jg = 16 * w + n16;   // W row this lane loads (A-frag m-index)
    const int jb = 16 * w + 4 * q; // first of the 4 h-cols this lane epilogues
    const int bbase = blockIdx.x * MT;

    // ---- prologue A: stage x = [z, embed(labels)] for 16 rows into LDS ----
    for (int c = t; c < MT * 24; c += 256) {    // 24 f32x4 chunks per row
        int m = c / 24, kk = (c % 24) * 4;
        f32x4 v;
        if (kk < 32) v = *(const f32x4*)(z + (size_t)(bbase + m) * 32 + kk);
        else         v = *(const f32x4*)(embed_w + labels[bbase + m] * 64 + (kk - 32));
        *(f32x4*)(xs + m * XSP + kk) = v;
    }

    // ---- persistent w_hh fragments: R,Z scaled by -L2E; N by +2*L2E ----
    // A[m = n16][k = q*8+j + 32ks] = scale[g] * w_hh[g*64 + jg][k]
    bf16x8 whi[3][2];
#pragma unroll
    for (int g = 0; g < 3; ++g) {
        const float wsc = (g == 2) ? (2.0f * L2E) : (-L2E);
        const float* pr = w_hh + (g * 64 + jg) * HDIM;
#pragma unroll
        for (int ks = 0; ks < 2; ++ks) {
            const float* p = pr + ks * 32 + q * 8;
            f32x4 va = *(const f32x4*)(p);
            f32x4 vb = *(const f32x4*)(p + 4);
#pragma unroll
            for (int j2 = 0; j2 < 4; ++j2) {
                whi[g][ks][j2]     = (__bf16)(va[j2] * wsc);
                whi[g][ks][4 + j2] = (__bf16)(vb[j2] * wsc);
            }
        }
    }

    // ---- output-head A fragments: A[m=n16][k] = out_w[n16][k] (n16<2 live) --
    bf16x8 obhi[2];
#pragma unroll
    for (int ks = 0; ks < 2; ++ks) {
        f32x4 va = {0.f, 0.f, 0.f, 0.f}, vb = {0.f, 0.f, 0.f, 0.f};
        if (n16 < 2) {
            va = *(const f32x4*)(out_w + n16 * 64 + ks * 32 + q * 8);
            vb = *(const f32x4*)(out_w + n16 * 64 + ks * 32 + q * 8 + 4);
        }
#pragma unroll
        for (int j2 = 0; j2 < 4; ++j2) {
            obhi[ks][j2]     = (__bf16)va[j2];
            obhi[ks][4 + j2] = (__bf16)vb[j2];
        }
    }
    // C/D bias by m-row (out-col): live rows m=0,1 sit at q==0, reg r=0,1
    const f32x4 obias = (q == 0) ? f32x4{out_b[0], out_b[1], 0.f, 0.f}
                                 : f32x4{0.f, 0.f, 0.f, 0.f};
    const f32x4 one4 = {1.f, 1.f, 1.f, 1.f};

    // every wave stores output for its 4 rows: q==0 lane, rows 4w..4w+3
    const bool ostorer = (q == 0) && ((n16 >> 2) == w);

    // per-lane gate constants: vectors over the lane's 4 cols jb..jb+3.
    // cR4/cZ4/bn4 are MFMA C-seeds (C reg r <-> gate col jb+r); bn4 is
    // 2L2E-scaled IN PLACE (same registers as R24's unscaled bn4).
    const f32x4 bihR = *(const f32x4*)(b_ih + jb);
    const f32x4 bhhR = *(const f32x4*)(b_hh + jb);
    const f32x4 bihZ = *(const f32x4*)(b_ih + 64 + jb);
    const f32x4 bhhZ = *(const f32x4*)(b_hh + 64 + jb);
    const f32x4 cR4 = (bihR + bhhR) * (-L2E);
    const f32x4 cZ4 = (bihZ + bhhZ) * (-L2E);
    const f32x4 bn4 = (*(const f32x4*)(b_hh + 128 + jb)) * (2.0f * L2E);
    const f32x4 cN4 = (*(const f32x4*)(b_ih + 128 + jb)) * (2.0f * L2E);

    const int rdoff = n16 * SB + q * 8;    // h B-frag offset (16B-aligned)
    const int wboff = n16 * SB + jb;       // state-write offset (8B-aligned)
    float* opb = out + (size_t)(bbase + n16) * (SEQ * 2);  // this lane's row

    __syncthreads();   // xs ready

    // ---- prologue B: h0 = tanh(fc_b + fc_w . x); lane -> row n16, 4 cols ----
    f32x4 hprev;
    {
        f32x4 a = *(const f32x4*)(fc_b + jb);
        for (int kc = 0; kc < 24; ++kc) {
            f32x4 xv = *(const f32x4*)(xs + n16 * XSP + kc * 4);
#pragma unroll
            for (int r = 0; r < 4; ++r) {
                f32x4 wv = *(const f32x4*)(fc_w + (size_t)(jb + r) * 96 + kc * 4);
                a[r] += wv[0] * xv[0] + wv[1] * xv[1] + wv[2] * xv[2] + wv[3] * xv[3];
            }
        }
        bf16x4 hp;
#pragma unroll
        for (int r = 0; r < 4; ++r) {
            hprev[r] = tanh_f(a[r]);
            hp[r] = (__bf16)hprev[r];
        }
        *(bf16x4*)(hbuf[0] + wboff) = hp;   // one ds_write_b64
    }
    __syncthreads();   // state 0 published in buf 0

    // Anti-phase the two co-resident blocks (i and i+256 share a CU).
    if ((blockIdx.x >> 8) & 1) __builtin_amdgcn_s_sleep(11);

    // previous step's b-frags for the deferred head (garbage first 2 iters;
    // computed unconditionally for wave balance, store is predicated)
    bf16x8 pb0 = {}, pb1 = {};

    for (int u = 0; u < SEQ / 4; ++u) {
#pragma unroll
        for (int s = 0; s < 4; ++s) {
            const int p = s & 1;
            const __bf16* Hh = hbuf[p];
            __bf16* Nh = hbuf[1 - p];

            // h B-frags of state i = 4u+s: B[k=q*8+j][n16] = h[n16][k]
            bf16x8 b0 = *(const bf16x8*)(Hh + rdoff);
            bf16x8 b1 = *(const bf16x8*)(Hh + rdoff + 32);

            // deferred output head (state i-1 -> out row i-2): register-only
            // MFMAs fill the ds_read lgkm-wait shadow right after the barrier
            {
                f32x4 o = obias;
                o = MFMA(obhi[0], pb0, o, 0, 0, 0);
                o = MFMA(obhi[1], pb1, o, 0, 0, 0);
                if ((u > 0 || s >= 2) && ostorer)
                    *(float2*)(opb + (8 * u + 2 * s - 4)) = make_float2(o[0], o[1]);
            }

            __builtin_amdgcn_s_setprio(1);

            // gates, bias-seeded & fully pre-scaled:
            // aR = -L2E*(W_R.h + bR_tot), aZ = -L2E*(W_Z.h + bZ_tot),
            // aN = 2L2E*(W_N.h + b_hhN)
            f32x4 aR, aZ, aN;
            aR = MFMA(whi[0][0], b0, cR4, 0, 0, 0);
            aZ = MFMA(whi[1][0], b0, cZ4, 0, 0, 0);
            aN = MFMA(whi[2][0], b0, bn4, 0, 0, 0);
            aR = MFMA(whi[0][1], b1, aR, 0, 0, 0);
            aZ = MFMA(whi[1][1], b1, aZ, 0, 0, 0);
            aN = MFMA(whi[2][1], b1, aN, 0, 0, 0);

            // fused epilogue: exp2 straight off the R/Z accumulators.
            // h' = [h*(eN+1) + eZ*(eN-1)] / [(eN+1)(1+eZ)]
            f32x4 eR, eZ;
#pragma unroll
            for (int r = 0; r < 4; ++r) {
                eR[r] = __builtin_amdgcn_exp2f(aR[r]);
                eZ[r] = __builtin_amdgcn_exp2f(aZ[r]);
            }
            f32x4 A = eR + one4;
            f32x4 rg;
#pragma unroll
            for (int r = 0; r < 4; ++r) rg[r] = __builtin_amdgcn_rcpf(A[r]);
            f32x4 tN = rg * aN + cN4;        // single fma: aN pre-scaled 2L2E
            f32x4 eN;
#pragma unroll
            for (int r = 0; r < 4; ++r) eN[r] = __builtin_amdgcn_exp2f(tN[r]);
            f32x4 wz = eZ + one4;            // 1 + eZ
            f32x4 pz = eZ + hprev;           // eZ + h
            f32x4 qz = hprev - eZ;           // h - eZ
            f32x4 Nst = eN * pz + qz;        // h*(eN+1) + eZ*(eN-1)
            f32x4 Dst = eN * wz + wz;        // (eN+1)*(1+eZ)
            f32x4 rD;
#pragma unroll
            for (int r = 0; r < 4; ++r) rD[r] = __builtin_amdgcn_rcpf(Dst[r]);
            f32x4 hn = Nst * rD;             // exact fp32 carry
            hprev = hn;
            bf16x4 hp;
#pragma unroll
            for (int r = 0; r < 4; ++r) hp[r] = (__bf16)hn[r];
            *(bf16x4*)(Nh + wboff) = hp;     // one ds_write_b64

            __builtin_amdgcn_s_setprio(0);

            pb0 = b0; pb1 = b1;              // renamed, not copied (unroll 4)

            BAR_LDS();   // state i+1 published (LDS-only drain; stores float)
        }
    }

    // tail: deferred head of state 179 (pb) -> row 178, then state 180 -> 179
    {
        f32x4 o = obias;
        o = MFMA(obhi[0], pb0, o, 0, 0, 0);
        o = MFMA(obhi[1], pb1, o, 0, 0, 0);
        if (ostorer)
            *(float2*)(opb + (SEQ - 2) * 2) = make_float2(o[0], o[1]);

        const __bf16* Hh = hbuf[0];
        bf16x8 b0 = *(const bf16x8*)(Hh + rdoff);
        bf16x8 b1 = *(const bf16x8*)(Hh + rdoff + 32);
        f32x4 o2 = obias;
        o2 = MFMA(obhi[0], b0, o2, 0, 0, 0);
        o2 = MFMA(obhi[1], b1, o2, 0, 0, 0);
        if (ostorer)
            *(float2*)(opb + (SEQ - 1) * 2) = make_float2(o2[0], o2[1]);
    }
}

extern "C" void kernel_launch(void* const* d_in, const int* in_sizes, int n_in,
                              void* d_out, int out_size, void* d_ws, size_t ws_size,
                              hipStream_t stream) {
    (void)in_sizes; (void)n_in; (void)out_size; (void)d_ws; (void)ws_size;
    const float* z       = (const float*)d_in[0];
    const int*   labels  = (const int*)d_in[1];
    const float* embed_w = (const float*)d_in[2];
    const float* fc_w    = (const float*)d_in[3];
    const float* fc_b    = (const float*)d_in[4];
    // d_in[5] = w_ih: unused (GRU input is all zeros; b_ih carries the effect)
    const float* w_hh    = (const float*)d_in[6];
    const float* b_ih    = (const float*)d_in[7];
    const float* b_hh    = (const float*)d_in[8];
    const float* out_w   = (const float*)d_in[9];
    const float* out_b   = (const float*)d_in[10];
    float* out = (float*)d_out;

    gru_all<<<NB / MT, 256, 0, stream>>>(z, labels, embed_w, fc_w, fc_b,
                                         w_hh, b_ih, b_hh, out_w, out_b, out);
}

// Round 15
// 160.774 us; speedup vs baseline: 1.1532x; 1.1532x over previous
//
#include <hip/hip_runtime.h>

#define NB     8192
#define HDIM   64
#define SEQ    180
#define MT     16     // batch rows per block
#define SB     72     // bf16 LDS row stride: 144 B, 16B-aligned (SB=68 regressed: misaligned b128)
#define XSP    100    // xs prologue row stride (floats)

typedef __bf16 bf16x8 __attribute__((ext_vector_type(8)));
typedef __bf16 bf16x4 __attribute__((ext_vector_type(4)));
typedef float  f32x4  __attribute__((ext_vector_type(4)));

#define L2E 1.44269504088896340736f

__device__ __forceinline__ float tanh_f(float x) {
    float e = __builtin_amdgcn_exp2f((2.0f * L2E) * x);
    return 1.0f - 2.0f * __builtin_amdgcn_rcpf(1.0f + e);
}

#define MFMA __builtin_amdgcn_mfma_f32_16x16x32_bf16

// In-loop barrier: LDS-only drain (R17: neutral vs __syncthreads; kept so the
// deferred head's global store floats across barriers).
#define BAR_LDS() asm volatile("s_waitcnt lgkmcnt(0)\n\ts_barrier" ::: "memory")

// R28 = R24 RESTORED VERBATIM (the proven best: 101.0us, VGPR 124).
// Final state of this session. Feature set:
//  - transposed gates G^T = W.h^T via 6 MFMA, R/Z weights pre-scaled by -L2E
//    with bias C-seeding (cR4/cZ4 as MFMA C operands) [R24: -5us]
//  - N gate C-seeded with raw bn4; tN = (rg*aN)*2L2E + cN4 kept EXACTLY in
//    this form: R21/R26/R27 all tried to fold the 2L2E mul away and all
//    tripped the 128-VGPR occupancy cliff (124->132, -20us). Near the cliff,
//    allocation is not monotone in source-level register count.
//  - fused 5-trans epilogue h' = [h(eN+1)+eZ(eN-1)]/[(eN+1)(1+eZ)] [R18]
//  - deferred output head in the post-barrier ds_read shadow [R18]
//  - 2 blocks/CU, 1 LDS-only barrier/step, one-shot sleep seed [R15/R17]
// Closed branches (all measured): sync tools (R20/R23/R25 neutral), dual
// chain (R16/R22 regress), MT=8 (R19 regress), N-fold (R21/R26/R27 cliff).
// Floor arithmetic: 20 trans x 16cy + ~90cy plain + 40cy MFMA ~ 430cy/wave
// issue, x2 waves + uncoverable LDS/barrier latency = ~1350cy period = 101us.
__global__ __launch_bounds__(256) void gru_all(
        const float* __restrict__ z, const int* __restrict__ labels,
        const float* __restrict__ embed_w, const float* __restrict__ fc_w,
        const float* __restrict__ fc_b, const float* __restrict__ w_hh,
        const float* __restrict__ b_ih, const float* __restrict__ b_hh,
        const float* __restrict__ out_w, const float* __restrict__ out_b,
        float* __restrict__ out) {
    __shared__ __align__(16) __bf16 hbuf[2][MT * SB];  // [buf] bf16(h)
    __shared__ __align__(16) float  xs[MT * XSP];      // h0 input [z|embed]

    const int t = threadIdx.x;
    const int w = t >> 6;          // wave 0..3
    const int l = t & 63;
    const int q = l >> 4;          // quad 0..3
    const int n16 = l & 15;
    const int jg = 16 * w + n16;   // W row this lane loads (A-frag m-index)
    const int jb = 16 * w + 4 * q; // first of the 4 h-cols this lane epilogues
    const int bbase = blockIdx.x * MT;

    // ---- prologue A: stage x = [z, embed(labels)] for 16 rows into LDS ----
    for (int c = t; c < MT * 24; c += 256) {    // 24 f32x4 chunks per row
        int m = c / 24, kk = (c % 24) * 4;
        f32x4 v;
        if (kk < 32) v = *(const f32x4*)(z + (size_t)(bbase + m) * 32 + kk);
        else         v = *(const f32x4*)(embed_w + labels[bbase + m] * 64 + (kk - 32));
        *(f32x4*)(xs + m * XSP + kk) = v;
    }

    // ---- persistent w_hh fragments: R,Z pre-scaled by -L2E; N plain ----
    // A[m = n16][k = q*8+j + 32ks] = scale[g] * w_hh[g*64 + jg][k]
    bf16x8 whi[3][2];
#pragma unroll
    for (int g = 0; g < 3; ++g) {
        const float wsc = (g == 2) ? 1.0f : (-L2E);
        const float* pr = w_hh + (g * 64 + jg) * HDIM;
#pragma unroll
        for (int ks = 0; ks < 2; ++ks) {
            const float* p = pr + ks * 32 + q * 8;
            f32x4 va = *(const f32x4*)(p);
            f32x4 vb = *(const f32x4*)(p + 4);
#pragma unroll
            for (int j2 = 0; j2 < 4; ++j2) {
                whi[g][ks][j2]     = (__bf16)(va[j2] * wsc);
                whi[g][ks][4 + j2] = (__bf16)(vb[j2] * wsc);
            }
        }
    }

    // ---- output-head A fragments: A[m=n16][k] = out_w[n16][k] (n16<2 live) --
    bf16x8 obhi[2];
#pragma unroll
    for (int ks = 0; ks < 2; ++ks) {
        f32x4 va = {0.f, 0.f, 0.f, 0.f}, vb = {0.f, 0.f, 0.f, 0.f};
        if (n16 < 2) {
            va = *(const f32x4*)(out_w + n16 * 64 + ks * 32 + q * 8);
            vb = *(const f32x4*)(out_w + n16 * 64 + ks * 32 + q * 8 + 4);
        }
#pragma unroll
        for (int j2 = 0; j2 < 4; ++j2) {
            obhi[ks][j2]     = (__bf16)va[j2];
            obhi[ks][4 + j2] = (__bf16)vb[j2];
        }
    }
    // C/D bias by m-row (out-col): live rows m=0,1 sit at q==0, reg r=0,1
    const f32x4 obias = (q == 0) ? f32x4{out_b[0], out_b[1], 0.f, 0.f}
                                 : f32x4{0.f, 0.f, 0.f, 0.f};
    const f32x4 one4 = {1.f, 1.f, 1.f, 1.f};

    // every wave stores output for its 4 rows: q==0 lane, rows 4w..4w+3
    const bool ostorer = (q == 0) && ((n16 >> 2) == w);

    // per-lane gate constants: vectors over the lane's 4 cols jb..jb+3.
    // cR4/cZ4/bn4 are MFMA C-seeds (C reg r <-> gate col jb+r, proven R21/R24).
    const f32x4 bihR = *(const f32x4*)(b_ih + jb);
    const f32x4 bhhR = *(const f32x4*)(b_hh + jb);
    const f32x4 bihZ = *(const f32x4*)(b_ih + 64 + jb);
    const f32x4 bhhZ = *(const f32x4*)(b_hh + 64 + jb);
    const f32x4 cR4 = (bihR + bhhR) * (-L2E);
    const f32x4 cZ4 = (bihZ + bhhZ) * (-L2E);
    const f32x4 bn4 = *(const f32x4*)(b_hh + 128 + jb);
    const f32x4 cN4 = (*(const f32x4*)(b_ih + 128 + jb)) * (2.0f * L2E);

    const int rdoff = n16 * SB + q * 8;    // h B-frag offset (16B-aligned)
    const int wboff = n16 * SB + jb;       // state-write offset (8B-aligned)
    float* opb = out + (size_t)(bbase + n16) * (SEQ * 2);  // this lane's row

    __syncthreads();   // xs ready

    // ---- prologue B: h0 = tanh(fc_b + fc_w . x); lane -> row n16, 4 cols ----
    f32x4 hprev;
    {
        f32x4 a = *(const f32x4*)(fc_b + jb);
        for (int kc = 0; kc < 24; ++kc) {
            f32x4 xv = *(const f32x4*)(xs + n16 * XSP + kc * 4);
#pragma unroll
            for (int r = 0; r < 4; ++r) {
                f32x4 wv = *(const f32x4*)(fc_w + (size_t)(jb + r) * 96 + kc * 4);
                a[r] += wv[0] * xv[0] + wv[1] * xv[1] + wv[2] * xv[2] + wv[3] * xv[3];
            }
        }
        bf16x4 hp;
#pragma unroll
        for (int r = 0; r < 4; ++r) {
            hprev[r] = tanh_f(a[r]);
            hp[r] = (__bf16)hprev[r];
        }
        *(bf16x4*)(hbuf[0] + wboff) = hp;   // one ds_write_b64
    }
    __syncthreads();   // state 0 published in buf 0

    // Anti-phase the two co-resident blocks (i and i+256 share a CU).
    if ((blockIdx.x >> 8) & 1) __builtin_amdgcn_s_sleep(11);

    // previous step's b-frags for the deferred head (garbage first 2 iters;
    // computed unconditionally for wave balance, store is predicated)
    bf16x8 pb0 = {}, pb1 = {};

    for (int u = 0; u < SEQ / 4; ++u) {
#pragma unroll
        for (int s = 0; s < 4; ++s) {
            const int p = s & 1;
            const __bf16* Hh = hbuf[p];
            __bf16* Nh = hbuf[1 - p];

            // h B-frags of state i = 4u+s: B[k=q*8+j][n16] = h[n16][k]
            bf16x8 b0 = *(const bf16x8*)(Hh + rdoff);
            bf16x8 b1 = *(const bf16x8*)(Hh + rdoff + 32);

            // deferred output head (state i-1 -> out row i-2): register-only
            // MFMAs fill the ds_read lgkm-wait shadow right after the barrier
            {
                f32x4 o = obias;
                o = MFMA(obhi[0], pb0, o, 0, 0, 0);
                o = MFMA(obhi[1], pb1, o, 0, 0, 0);
                if ((u > 0 || s >= 2) && ostorer)
                    *(float2*)(opb + (8 * u + 2 * s - 4)) = make_float2(o[0], o[1]);
            }

            __builtin_amdgcn_s_setprio(1);

            // gates, bias-seeded: aR = -L2E*(W_R.h + bR_tot),
            // aZ = -L2E*(W_Z.h + bZ_tot), aN = W_N.h + b_hhN
            f32x4 aR, aZ, aN;
            aR = MFMA(whi[0][0], b0, cR4, 0, 0, 0);
            aZ = MFMA(whi[1][0], b0, cZ4, 0, 0, 0);
            aN = MFMA(whi[2][0], b0, bn4, 0, 0, 0);
            aR = MFMA(whi[0][1], b1, aR, 0, 0, 0);
            aZ = MFMA(whi[1][1], b1, aZ, 0, 0, 0);
            aN = MFMA(whi[2][1], b1, aN, 0, 0, 0);

            // fused epilogue: exp2 straight off the R/Z accumulators.
            // h' = [h*(eN+1) + eZ*(eN-1)] / [(eN+1)(1+eZ)]
            f32x4 eR, eZ;
#pragma unroll
            for (int r = 0; r < 4; ++r) {
                eR[r] = __builtin_amdgcn_exp2f(aR[r]);
                eZ[r] = __builtin_amdgcn_exp2f(aZ[r]);
            }
            f32x4 A = eR + one4;
            f32x4 rg;
#pragma unroll
            for (int r = 0; r < 4; ++r) rg[r] = __builtin_amdgcn_rcpf(A[r]);
            f32x4 tN = (rg * aN) * (2.0f * L2E) + cN4;   // aN already has bn4
            f32x4 eN;
#pragma unroll
            for (int r = 0; r < 4; ++r) eN[r] = __builtin_amdgcn_exp2f(tN[r]);
            f32x4 wz = eZ + one4;            // 1 + eZ
            f32x4 pz = eZ + hprev;           // eZ + h
            f32x4 qz = hprev - eZ;           // h - eZ
            f32x4 Nst = eN * pz + qz;        // h*(eN+1) + eZ*(eN-1)
            f32x4 Dst = eN * wz + wz;        // (eN+1)*(1+eZ)
            f32x4 rD;
#pragma unroll
            for (int r = 0; r < 4; ++r) rD[r] = __builtin_amdgcn_rcpf(Dst[r]);
            f32x4 hn = Nst * rD;             // exact fp32 carry
            hprev = hn;
            bf16x4 hp;
#pragma unroll
            for (int r = 0; r < 4; ++r) hp[r] = (__bf16)hn[r];
            *(bf16x4*)(Nh + wboff) = hp;     // one ds_write_b64

            __builtin_amdgcn_s_setprio(0);

            pb0 = b0; pb1 = b1;              // renamed, not copied (unroll 4)

            BAR_LDS();   // state i+1 published (LDS-only drain; stores float)
        }
    }

    // tail: deferred head of state 179 (pb) -> row 178, then state 180 -> 179
    {
        f32x4 o = obias;
        o = MFMA(obhi[0], pb0, o, 0, 0, 0);
        o = MFMA(obhi[1], pb1, o, 0, 0, 0);
        if (ostorer)
            *(float2*)(opb + (SEQ - 2) * 2) = make_float2(o[0], o[1]);

        const __bf16* Hh = hbuf[0];
        bf16x8 b0 = *(const bf16x8*)(Hh + rdoff);
        bf16x8 b1 = *(const bf16x8*)(Hh + rdoff + 32);
        f32x4 o2 = obias;
        o2 = MFMA(obhi[0], b0, o2, 0, 0, 0);
        o2 = MFMA(obhi[1], b1, o2, 0, 0, 0);
        if (ostorer)
            *(float2*)(opb + (SEQ - 1) * 2) = make_float2(o2[0], o2[1]);
    }
}

extern "C" void kernel_launch(void* const* d_in, const int* in_sizes, int n_in,
                              void* d_out, int out_size, void* d_ws, size_t ws_size,
                              hipStream_t stream) {
    (void)in_sizes; (void)n_in; (void)out_size; (void)d_ws; (void)ws_size;
    const float* z       = (const float*)d_in[0];
    const int*   labels  = (const int*)d_in[1];
    const float* embed_w = (const float*)d_in[2];
    const float* fc_w    = (const float*)d_in[3];
    const float* fc_b    = (const float*)d_in[4];
    // d_in[5] = w_ih: unused (GRU input is all zeros; b_ih carries the effect)
    const float* w_hh    = (const float*)d_in[6];
    const float* b_ih    = (const float*)d_in[7];
    const float* b_hh    = (const float*)d_in[8];
    const float* out_w   = (const float*)d_in[9];
    const float* out_b   = (const float*)d_in[10];
    float* out = (float*)d_out;

    gru_all<<<NB / MT, 256, 0, stream>>>(z, labels, embed_w, fc_w, fc_b,
                                         w_hh, b_ih, b_hh, out_w, out_b, out);
}